// Round 5
// baseline (320.176 us; speedup 1.0000x reference)
//
#include <hip/hip_runtime.h>

// TokenMixer: out[n,b,c] = x_pos[n,b,c] * (1 - sigmoid(cos_sim(x_pre[n,b,:], x_pos[n,b,:])))
// N=4096, B=16, C=512 -> 65536 rows of 512 fp32. Inputs fp32, output fp32.
//
// Round-5 vs round-4 (112 us): waves were one-shot (load -> 6-deep shuffle
// chain with no memory in flight -> retire), per-wave lifetime ~46K cycles for
// ~2K cycles of work. Fix:
//  1. 8 rows per wave as 4 software-pipelined iterations x 2 rows, register
//     double-buffer: iter k+1's 8KB of loads issue BEFORE iter k's reduction
//     waits -> memory stays in flight across the shuffle chain; per-wave
//     launch cost amortized 4x.
//  2. Non-temporal output stores: stop the 134MB output stream from evicting
//     L3-resident input lines (harness restore leaves inputs L3-hot; FETCH
//     was only half the input bytes).

constexpr int C_DIM = 512;
constexpr int ROWS  = 4096 * 16;     // 65536
constexpr int ITERS = 4;             // row-pairs per wave -> 8 rows/wave

typedef float f32x4 __attribute__((ext_vector_type(4)));

__device__ __forceinline__ void load4(const float* __restrict__ p, size_t b,
                                      float4 v[4]) {
    v[0] = *reinterpret_cast<const float4*>(p + b);
    v[1] = *reinterpret_cast<const float4*>(p + b + 256);
    v[2] = *reinterpret_cast<const float4*>(p + b + 512);
    v[3] = *reinterpret_cast<const float4*>(p + b + 768);
}

__device__ __forceinline__ void store_nt(float* p, float4 v) {
    __builtin_nontemporal_store(*reinterpret_cast<f32x4*>(&v),
                                reinterpret_cast<f32x4*>(p));
}

__device__ __forceinline__ void partials(const float4& p, const float4& q,
                                         float& s_pre, float& s_pos, float& dot) {
    s_pre = fmaf(p.x, p.x, s_pre); s_pre = fmaf(p.y, p.y, s_pre);
    s_pre = fmaf(p.z, p.z, s_pre); s_pre = fmaf(p.w, p.w, s_pre);
    s_pos = fmaf(q.x, q.x, s_pos); s_pos = fmaf(q.y, q.y, s_pos);
    s_pos = fmaf(q.z, q.z, s_pos); s_pos = fmaf(q.w, q.w, s_pos);
    dot   = fmaf(p.x, q.x, dot);   dot   = fmaf(p.y, q.y, dot);
    dot   = fmaf(p.z, q.z, dot);   dot   = fmaf(p.w, q.w, dot);
}

__global__ __launch_bounds__(256) void tokenmixer_kernel(
    const float* __restrict__ pre,
    const float* __restrict__ pos,
    float* __restrict__ out)
{
    const int wave = (int)((blockIdx.x * 256u + threadIdx.x) >> 6);
    const int lane = (int)(threadIdx.x & 63u);

    // wave owns 8 consecutive rows = ITERS iterations of 2 rows (2048 B/iter
    // per tensor); lane owns the float4 at lane*16B of each 1024-B segment.
    const size_t base = (size_t)wave * (ITERS * 2 * C_DIM) + (size_t)lane * 4;

    float4 P[2][4], Q[2][4];
    load4(pre, base, P[0]);
    load4(pos, base, Q[0]);

#pragma unroll
    for (int k = 0; k < ITERS; ++k) {
        const int cur = k & 1;
        const int nxt = cur ^ 1;
        const size_t cb = base + (size_t)k * (2 * C_DIM);

        // prefetch next row-pair before waiting on current (keeps vmem busy
        // through the shuffle chain below)
        if (k + 1 < ITERS) {
            load4(pre, cb + 2 * C_DIM, P[nxt]);
            load4(pos, cb + 2 * C_DIM, Q[nxt]);
        }

        float sp0 = 0.f, sq0 = 0.f, d0 = 0.f;   // row 2k
        float sp1 = 0.f, sq1 = 0.f, d1 = 0.f;   // row 2k+1
        partials(P[cur][0], Q[cur][0], sp0, sq0, d0);
        partials(P[cur][1], Q[cur][1], sp0, sq0, d0);
        partials(P[cur][2], Q[cur][2], sp1, sq1, d1);
        partials(P[cur][3], Q[cur][3], sp1, sq1, d1);

        // 64-lane butterfly reduction, 6 values interleaved (ILP=6 per step)
#pragma unroll
        for (int m = 1; m < 64; m <<= 1) {
            sp0 += __shfl_xor(sp0, m, 64);
            sq0 += __shfl_xor(sq0, m, 64);
            d0  += __shfl_xor(d0,  m, 64);
            sp1 += __shfl_xor(sp1, m, 64);
            sq1 += __shfl_xor(sq1, m, 64);
            d1  += __shfl_xor(d1,  m, 64);
        }

        const float c0 = d0 / (fmaxf(sqrtf(sp0), 1e-12f) * fmaxf(sqrtf(sq0), 1e-12f));
        const float c1 = d1 / (fmaxf(sqrtf(sp1), 1e-12f) * fmaxf(sqrtf(sq1), 1e-12f));
        const float w0 = 1.0f / (1.0f + __expf(c0));   // 1 - sigmoid
        const float w1 = 1.0f / (1.0f + __expf(c1));

        float4 o;
        o.x = Q[cur][0].x * w0; o.y = Q[cur][0].y * w0;
        o.z = Q[cur][0].z * w0; o.w = Q[cur][0].w * w0;
        store_nt(out + cb, o);
        o.x = Q[cur][1].x * w0; o.y = Q[cur][1].y * w0;
        o.z = Q[cur][1].z * w0; o.w = Q[cur][1].w * w0;
        store_nt(out + cb + 256, o);
        o.x = Q[cur][2].x * w1; o.y = Q[cur][2].y * w1;
        o.z = Q[cur][2].z * w1; o.w = Q[cur][2].w * w1;
        store_nt(out + cb + 512, o);
        o.x = Q[cur][3].x * w1; o.y = Q[cur][3].y * w1;
        o.z = Q[cur][3].z * w1; o.w = Q[cur][3].w * w1;
        store_nt(out + cb + 768, o);
    }
}

extern "C" void kernel_launch(void* const* d_in, const int* in_sizes, int n_in,
                              void* d_out, int out_size, void* d_ws, size_t ws_size,
                              hipStream_t stream) {
    const float* pre = (const float*)d_in[0];
    const float* pos = (const float*)d_in[1];
    float* out = (float*)d_out;

    // 8 rows per wave, 4 waves per block -> 32 rows per block
    const int blocks = ROWS / 32;  // 2048
    tokenmixer_kernel<<<blocks, 256, 0, stream>>>(pre, pos, out);
}